// Round 3
// baseline (708.253 us; speedup 1.0000x reference)
//
#include <hip/hip_runtime.h>
#include <math.h>

// ---------------------------------------------------------------------------
// QuantBasicTransformerBlock on MI355X (gfx950).
// FP32 buffers in/out (reference dtypes); bf16 MFMA internally.
// B=4 N=1024 D=1024 H=16 DH=64 CTX_N=77 CTX_D=768 FF_HID=4096
//
// Workspace (80 MB):
//   W    0..16  bf16 transposed weights (JIT, reused per phase)
//   lnb 16..24  LN out bf16 [4096][1024]
//   qb  24..32  quant Q ints-in-bf16
//   kb  32..40  quant K | cross: k2b 32..33, v2b 33..34, ctxb 34..35
//   vb  40..48  quant V | x2 32..48 fp32 (after attn2)
//   ao  48..56  attn out bf16 | gg 48..80 bf16 [4096][4096] (FF)
//   x1  56..72  fp32 trunk after attn1
// ---------------------------------------------------------------------------

typedef unsigned short u16;
typedef __attribute__((ext_vector_type(8))) short short8;   // 8 bf16 = 4 VGPR
typedef __attribute__((ext_vector_type(4))) float f32x4;

__device__ inline float b2f(u16 v) { return __uint_as_float(((unsigned)v) << 16); }
__device__ inline u16 f2b(float f) {             // round-to-nearest-even
  unsigned u = __float_as_uint(f);
  unsigned r = u + 0x7fffu + ((u >> 16) & 1u);
  return (u16)(r >> 16);
}

// ---------------------------------------------------------------------------
// fp32 -> bf16 cast, 4 elements/thread. n must be divisible by 1024.
// ---------------------------------------------------------------------------
__global__ __launch_bounds__(256) void cast_k(const float* __restrict__ in,
                                              u16* __restrict__ out) {
  int i = (blockIdx.x * 256 + threadIdx.x) * 4;
  float4 v = *(const float4*)(in + i);
  out[i + 0] = f2b(v.x);
  out[i + 1] = f2b(v.y);
  out[i + 2] = f2b(v.z);
  out[i + 3] = f2b(v.w);
}

// ---------------------------------------------------------------------------
// Transpose fp32 in[R][C] -> bf16 out[C][R].  R,C multiples of 32.
// ---------------------------------------------------------------------------
__global__ __launch_bounds__(256) void transpose_k(const float* __restrict__ in,
                                                   u16* __restrict__ out,
                                                   int R, int C) {
  __shared__ float t[32][33];
  int tx = threadIdx.x & 31, ty = threadIdx.x >> 5;  // 32 x 8
  int c0 = blockIdx.x * 32, r0 = blockIdx.y * 32;
#pragma unroll
  for (int i = 0; i < 32; i += 8)
    t[ty + i][tx] = in[(size_t)(r0 + ty + i) * C + c0 + tx];
  __syncthreads();
#pragma unroll
  for (int i = 0; i < 32; i += 8)
    out[(size_t)(c0 + ty + i) * R + r0 + tx] = f2b(t[tx][ty + i]);
}

// ---------------------------------------------------------------------------
// LayerNorm over D=1024 (fp32 in, bf16 out). One block per row.
// ---------------------------------------------------------------------------
__global__ __launch_bounds__(256) void ln_k(const float* __restrict__ X,
                                            const float* __restrict__ W,
                                            const float* __restrict__ Bi,
                                            u16* __restrict__ Out) {
  const int row = blockIdx.x, tid = threadIdx.x;
  float4 x = *(const float4*)(X + (size_t)row * 1024 + tid * 4);
  float s = x.x + x.y + x.z + x.w;
  float s2 = x.x * x.x + x.y * x.y + x.z * x.z + x.w * x.w;
#pragma unroll
  for (int off = 32; off >= 1; off >>= 1) {
    s += __shfl_down(s, off);
    s2 += __shfl_down(s2, off);
  }
  __shared__ float red[8];
  int wave = tid >> 6, lane = tid & 63;
  if (lane == 0) { red[wave] = s; red[4 + wave] = s2; }
  __syncthreads();
  s = red[0] + red[1] + red[2] + red[3];
  s2 = red[4] + red[5] + red[6] + red[7];
  float mean = s * 0.0009765625f;
  float var = s2 * 0.0009765625f - mean * mean;
  float rs = rsqrtf(var + 1e-5f);
  float4 w = *(const float4*)(W + tid * 4);
  float4 b = *(const float4*)(Bi + tid * 4);
  u16* orow = Out + (size_t)row * 1024 + tid * 4;
  orow[0] = f2b((x.x - mean) * rs * w.x + b.x);
  orow[1] = f2b((x.y - mean) * rs * w.y + b.y);
  orow[2] = f2b((x.z - mean) * rs * w.z + b.z);
  orow[3] = f2b((x.w - mean) * rs * w.w + b.w);
}

// ---------------------------------------------------------------------------
// GEMM: C[M,N] = A[M,K] (bf16) @ B[K,N] given as Bt[N,K] (bf16).
// 128x128 tile, BK=64, 4 waves x (4x4) 16x16x32 MFMA. Layouts per m89/m120:
//   A-frag a[j]=A[m=lane&15][k=(lane>>4)*8+j]; B-frag b[j]=Bt[n=lane&15][k=..]
//   D d[r]: row=(lane>>4)*4+r, col=lane&15
// EPI: 0 = fake-quant -> int-in-bf16;  1 = +bias +fp32 residual -> fp32
// ---------------------------------------------------------------------------
template <int EPI>
__global__ __launch_bounds__(256, 2) void gemm_bt(
    const u16* __restrict__ A, int lda, const u16* __restrict__ Bt, int ldb,
    void* __restrict__ Cp, int ldc, const float* __restrict__ bias,
    const float* __restrict__ res, int ldr, const float* __restrict__ dp,
    int M, int N, int K) {
  __shared__ __align__(16) u16 As[128][72];
  __shared__ __align__(16) u16 Bs[128][72];
  const int tid = threadIdx.x;
  const int lane = tid & 63, wave = tid >> 6;
  const int qd = lane >> 4, cl = lane & 15;
  const int wm = (wave & 1) << 6, wn = (wave >> 1) << 6;
  const int m0 = blockIdx.x * 128, n0 = blockIdx.y * 128;

  f32x4 acc[4][4];
  const f32x4 zero = {0.f, 0.f, 0.f, 0.f};
#pragma unroll
  for (int i = 0; i < 4; i++)
#pragma unroll
    for (int j = 0; j < 4; j++) acc[i][j] = zero;

  for (int k0 = 0; k0 < K; k0 += 64) {
    __syncthreads();
#pragma unroll
    for (int it = 0; it < 4; ++it) {
      int ch = it * 256 + tid;
      int r = ch >> 3, cc = (ch & 7) << 3;
      int gr = m0 + r;
      gr = gr < M ? gr : M - 1;  // clamp reads; stores guarded below
      *(uint4*)(&As[r][cc]) = *(const uint4*)(A + (size_t)gr * lda + k0 + cc);
      *(uint4*)(&Bs[r][cc]) =
          *(const uint4*)(Bt + (size_t)(n0 + r) * ldb + k0 + cc);
    }
    __syncthreads();
#pragma unroll
    for (int ks = 0; ks < 64; ks += 32) {
      short8 af[4], bf[4];
#pragma unroll
      for (int t = 0; t < 4; t++)
        af[t] = *(const short8*)(&As[wm + t * 16 + cl][ks + qd * 8]);
#pragma unroll
      for (int t = 0; t < 4; t++)
        bf[t] = *(const short8*)(&Bs[wn + t * 16 + cl][ks + qd * 8]);
#pragma unroll
      for (int mt = 0; mt < 4; mt++)
#pragma unroll
        for (int nt = 0; nt < 4; nt++)
          acc[mt][nt] = __builtin_amdgcn_mfma_f32_16x16x32_bf16(
              af[mt], bf[nt], acc[mt][nt], 0, 0, 0);
    }
  }

  float dscale = 1.f;
  if constexpr (EPI == 0) dscale = 1.0f / dp[0];
#pragma unroll
  for (int mt = 0; mt < 4; ++mt) {
#pragma unroll
    for (int r = 0; r < 4; ++r) {
      int row = m0 + wm + mt * 16 + qd * 4 + r;
      if (row >= M) continue;
#pragma unroll
      for (int nt = 0; nt < 4; ++nt) {
        int col = n0 + wn + nt * 16 + cl;
        float v = acc[mt][nt][r];
        if constexpr (EPI == 0) {
          // clip(rint(v/d)+128, 0,255)-128, exact small int in bf16
          float xq = rintf(v * dscale) + 128.f;
          xq = fminf(fmaxf(xq, 0.f), 255.f);
          ((u16*)Cp)[(size_t)row * ldc + col] = f2b(xq - 128.f);
        } else {
          v += bias[col] + res[(size_t)row * ldr + col];
          ((float*)Cp)[(size_t)row * ldc + col] = v;
        }
      }
    }
  }
}

// ---------------------------------------------------------------------------
// Fused FF1 + GEGLU: gg[M,4096] = (lnb@W1a + b1a) * gelu(lnb@W1g + b1g),
// W1t bf16 [8192][1024]. Tile 128x64; per wave 64x32, dual accumulators.
// ---------------------------------------------------------------------------
__global__ __launch_bounds__(256, 2) void ff1_geglu_k(
    const u16* __restrict__ A, const u16* __restrict__ W1t,
    const float* __restrict__ b1, u16* __restrict__ gg, int M) {
  __shared__ __align__(16) u16 As[128][72];
  __shared__ __align__(16) u16 Ba[64][72];
  __shared__ __align__(16) u16 Bg[64][72];
  const int tid = threadIdx.x;
  const int lane = tid & 63, wave = tid >> 6;
  const int qd = lane >> 4, cl = lane & 15;
  const int wm = (wave & 1) << 6, wn = (wave >> 1) << 5;
  const int m0 = blockIdx.x * 128, n0 = blockIdx.y * 64;

  f32x4 aca[4][2], acg[4][2];
  const f32x4 zero = {0.f, 0.f, 0.f, 0.f};
#pragma unroll
  for (int i = 0; i < 4; i++)
#pragma unroll
    for (int j = 0; j < 2; j++) { aca[i][j] = zero; acg[i][j] = zero; }

  for (int k0 = 0; k0 < 1024; k0 += 64) {
    __syncthreads();
#pragma unroll
    for (int it = 0; it < 4; ++it) {
      int ch = it * 256 + tid;
      int r = ch >> 3, cc = (ch & 7) << 3;
      *(uint4*)(&As[r][cc]) =
          *(const uint4*)(A + (size_t)(m0 + r) * 1024 + k0 + cc);
    }
#pragma unroll
    for (int it = 0; it < 2; ++it) {
      int ch = it * 256 + tid;
      int r = ch >> 3, cc = (ch & 7) << 3;
      *(uint4*)(&Ba[r][cc]) =
          *(const uint4*)(W1t + (size_t)(n0 + r) * 1024 + k0 + cc);
      *(uint4*)(&Bg[r][cc]) =
          *(const uint4*)(W1t + (size_t)(4096 + n0 + r) * 1024 + k0 + cc);
    }
    __syncthreads();
#pragma unroll
    for (int ks = 0; ks < 64; ks += 32) {
      short8 af[4], ba[2], bg[2];
#pragma unroll
      for (int t = 0; t < 4; t++)
        af[t] = *(const short8*)(&As[wm + t * 16 + cl][ks + qd * 8]);
#pragma unroll
      for (int t = 0; t < 2; t++) {
        ba[t] = *(const short8*)(&Ba[wn + t * 16 + cl][ks + qd * 8]);
        bg[t] = *(const short8*)(&Bg[wn + t * 16 + cl][ks + qd * 8]);
      }
#pragma unroll
      for (int mt = 0; mt < 4; mt++)
#pragma unroll
        for (int nt = 0; nt < 2; nt++) {
          aca[mt][nt] = __builtin_amdgcn_mfma_f32_16x16x32_bf16(
              af[mt], ba[nt], aca[mt][nt], 0, 0, 0);
          acg[mt][nt] = __builtin_amdgcn_mfma_f32_16x16x32_bf16(
              af[mt], bg[nt], acg[mt][nt], 0, 0, 0);
        }
    }
  }
#pragma unroll
  for (int mt = 0; mt < 4; ++mt)
#pragma unroll
    for (int r = 0; r < 4; ++r) {
      int row = m0 + wm + mt * 16 + qd * 4 + r;
#pragma unroll
      for (int nt = 0; nt < 2; ++nt) {
        int col = n0 + wn + nt * 16 + cl;
        float a = aca[mt][nt][r] + b1[col];
        float g = acg[mt][nt][r] + b1[4096 + col];
        float ge = 0.5f * g * (1.0f + erff(g * 0.70710678118654752f));
        gg[(size_t)row * 4096 + col] = f2b(a * ge);
      }
    }
}

// ---------------------------------------------------------------------------
// Two-pass quantized attention. Q/K/V hold quantized INTEGER values (-128..127)
// in bf16 (exact); MFMA dots are exact int sums in fp32. Block = 64 q-rows of
// one (b,h); wave = 16 rows. Pass A: softmax stats. Pass B: quantize P
// (ints 0..255, exact in bf16), P@V with LDS round-trip (m120 pattern).
// ---------------------------------------------------------------------------
__global__ __launch_bounds__(256, 2) void attn_k(
    const u16* __restrict__ Q, const u16* __restrict__ Kb,
    const u16* __restrict__ Vb, u16* __restrict__ O,
    const float* dqp, const float* dkp, const float* dvp, const float* dwp,
    int NK) {
  __shared__ __align__(16) u16 Qs[64][72];
  __shared__ __align__(16) u16 Ks[64][72];
  __shared__ __align__(16) u16 Vs[64][72];      // transposed: Vs[d][key]
  __shared__ __align__(16) u16 Ps[4][16][72];   // per-wave quantized P
  const int tid = threadIdx.x;
  const int lane = tid & 63, wave = tid >> 6;
  const int qd = lane >> 4, cl = lane & 15;
  const int b = blockIdx.z, h = blockIdx.y, qt = blockIdx.x;
  const float sscale = dqp[0] * dkp[0] * 0.125f;  // dq*dk*DH^-0.5
  const float oscale = dwp[0] * dvp[0];
  const float inv_dw = 1.0f / dwp[0];

#pragma unroll
  for (int it = 0; it < 2; ++it) {  // stage Q tile [64 rows][64 dims]
    int ch = it * 256 + tid;
    int r = ch >> 3, cc = (ch & 7) << 3;
    *(uint4*)(&Qs[r][cc]) = *(const uint4*)(
        Q + (size_t)(b * 1024 + qt * 64 + r) * 1024 + h * 64 + cc);
  }
  __syncthreads();
  short8 qf[2];
#pragma unroll
  for (int ks = 0; ks < 2; ++ks)
    qf[ks] = *(const short8*)(&Qs[wave * 16 + cl][ks * 32 + qd * 8]);

  float m_r[4], l_r[4];
#pragma unroll
  for (int r = 0; r < 4; r++) { m_r[r] = -1e30f; l_r[r] = 0.f; }

  // ---------------- PASS A: row max + denom ----------------
  for (int j0 = 0; j0 < NK; j0 += 64) {
    __syncthreads();
#pragma unroll
    for (int it = 0; it < 2; ++it) {
      int ch = it * 256 + tid;
      int r = ch >> 3, cc = (ch & 7) << 3;
      int j = j0 + r;
      j = j < NK ? j : NK - 1;  // clamp; masked below
      *(uint4*)(&Ks[r][cc]) =
          *(const uint4*)(Kb + (size_t)(b * NK + j) * 1024 + h * 64 + cc);
    }
    __syncthreads();
    float sv[4][4];
#pragma unroll
    for (int nt = 0; nt < 4; ++nt) {
      f32x4 s = {0.f, 0.f, 0.f, 0.f};
#pragma unroll
      for (int ks = 0; ks < 2; ++ks) {
        short8 kf = *(const short8*)(&Ks[nt * 16 + cl][ks * 32 + qd * 8]);
        s = __builtin_amdgcn_mfma_f32_16x16x32_bf16(qf[ks], kf, s, 0, 0, 0);
      }
      int key = j0 + nt * 16 + cl;
#pragma unroll
      for (int r = 0; r < 4; r++)
        sv[nt][r] = (key < NK) ? s[r] * sscale : -1e30f;
    }
#pragma unroll
    for (int r = 0; r < 4; r++) {
      float mx = fmaxf(fmaxf(sv[0][r], sv[1][r]), fmaxf(sv[2][r], sv[3][r]));
#pragma unroll
      for (int off = 1; off < 16; off <<= 1) mx = fmaxf(mx, __shfl_xor(mx, off));
      float mn = fmaxf(m_r[r], mx);
      float ss = __expf(sv[0][r] - mn) + __expf(sv[1][r] - mn) +
                 __expf(sv[2][r] - mn) + __expf(sv[3][r] - mn);
#pragma unroll
      for (int off = 1; off < 16; off <<= 1) ss += __shfl_xor(ss, off);
      l_r[r] = l_r[r] * __expf(m_r[r] - mn) + ss;
      m_r[r] = mn;
    }
  }
  float il[4];
#pragma unroll
  for (int r = 0; r < 4; r++) il[r] = 1.0f / l_r[r];

  f32x4 oacc[4];
  const f32x4 zero = {0.f, 0.f, 0.f, 0.f};
#pragma unroll
  for (int t = 0; t < 4; t++) oacc[t] = zero;

  // ---------------- PASS B: quantize P, P@V ----------------
  for (int j0 = 0; j0 < NK; j0 += 64) {
    __syncthreads();
#pragma unroll
    for (int it = 0; it < 2; ++it) {
      int ch = it * 256 + tid;
      int r = ch >> 3, cc = (ch & 7) << 3;
      int j = j0 + r;
      j = j < NK ? j : NK - 1;
      *(uint4*)(&Ks[r][cc]) =
          *(const uint4*)(Kb + (size_t)(b * NK + j) * 1024 + h * 64 + cc);
      union { uint4 v; u16 s[8]; } tmp;
      tmp.v = *(const uint4*)(Vb + (size_t)(b * NK + j) * 1024 + h * 64 + cc);
#pragma unroll
      for (int i = 0; i < 8; i++) Vs[cc + i][r] = tmp.s[i];  // transpose
    }
    __syncthreads();
#pragma unroll
    for (int nt = 0; nt < 4; ++nt) {
      f32x4 s = {0.f, 0.f, 0.f, 0.f};
#pragma unroll
      for (int ks = 0; ks < 2; ++ks) {
        short8 kf = *(const short8*)(&Ks[nt * 16 + cl][ks * 32 + qd * 8]);
        s = __builtin_amdgcn_mfma_f32_16x16x32_bf16(qf[ks], kf, s, 0, 0, 0);
      }
      int key = j0 + nt * 16 + cl;
#pragma unroll
      for (int r = 0; r < 4; r++) {
        float aw = 0.f;
        if (key < NK) {
          float attn = __expf(s[r] * sscale - m_r[r]) * il[r];
          aw = rintf(attn * inv_dw);
          aw = fminf(fmaxf(aw, 0.f), 255.f);
        }
        Ps[wave][qd * 4 + r][nt * 16 + cl] = f2b(aw);  // D-layout -> LDS
      }
    }
    __syncthreads();
#pragma unroll
    for (int ks = 0; ks < 2; ++ks) {
      short8 pf = *(const short8*)(&Ps[wave][cl][ks * 32 + qd * 8]);  // A-frag
#pragma unroll
      for (int dt = 0; dt < 4; ++dt) {
        short8 vf = *(const short8*)(&Vs[dt * 16 + cl][ks * 32 + qd * 8]);
        oacc[dt] =
            __builtin_amdgcn_mfma_f32_16x16x32_bf16(pf, vf, oacc[dt], 0, 0, 0);
      }
    }
  }
#pragma unroll
  for (int dt = 0; dt < 4; ++dt)
#pragma unroll
    for (int r = 0; r < 4; r++) {
      size_t addr =
          (size_t)(b * 1024 + qt * 64 + wave * 16 + qd * 4 + r) * 1024 +
          h * 64 + dt * 16 + cl;
      O[addr] = f2b(oacc[dt][r] * oscale);
    }
}

// ---------------------------------------------------------------------------
extern "C" void kernel_launch(void* const* d_in, const int* in_sizes, int n_in,
                              void* d_out, int out_size, void* d_ws,
                              size_t ws_size, hipStream_t stream) {
  (void)in_sizes; (void)n_in; (void)out_size; (void)ws_size;
  const float* x    = (const float*)d_in[0];
  const float* ctx  = (const float*)d_in[1];
  const float* n1w  = (const float*)d_in[2];
  const float* n1b  = (const float*)d_in[3];
  const float* n2w  = (const float*)d_in[4];
  const float* n2b  = (const float*)d_in[5];
  const float* n3w  = (const float*)d_in[6];
  const float* n3b  = (const float*)d_in[7];
  const float* a1wq = (const float*)d_in[8];
  const float* a1wk = (const float*)d_in[9];
  const float* a1wv = (const float*)d_in[10];
  const float* a1wo = (const float*)d_in[11];
  const float* a1bo = (const float*)d_in[12];
  const float* a2wq = (const float*)d_in[13];
  const float* a2wk = (const float*)d_in[14];
  const float* a2wv = (const float*)d_in[15];
  const float* a2wo = (const float*)d_in[16];
  const float* a2bo = (const float*)d_in[17];
  const float* ffw1 = (const float*)d_in[18];
  const float* ffb1 = (const float*)d_in[19];
  const float* ffw2 = (const float*)d_in[20];
  const float* ffb2 = (const float*)d_in[21];
  const float* d1q = (const float*)d_in[22];
  const float* d1k = (const float*)d_in[23];
  const float* d1v = (const float*)d_in[24];
  const float* d1w = (const float*)d_in[25];
  const float* d2q = (const float*)d_in[26];
  const float* d2k = (const float*)d_in[27];
  const float* d2v = (const float*)d_in[28];
  const float* d2w = (const float*)d_in[29];

  char* ws = (char*)d_ws;
  const size_t MB = 1u << 20;
  u16* W    = (u16*)(ws + 0 * MB);    // 16 MB JIT bf16 weight region
  u16* lnb  = (u16*)(ws + 16 * MB);   // [4096][1024] bf16
  u16* qb   = (u16*)(ws + 24 * MB);
  u16* kb   = (u16*)(ws + 32 * MB);
  u16* vb   = (u16*)(ws + 40 * MB);
  u16* ao   = (u16*)(ws + 48 * MB);
  float* x1 = (float*)(ws + 56 * MB); // fp32 trunk -> 72 MB
  u16* k2b  = (u16*)(ws + 32 * MB);   // [308][1024] (kb dead)
  u16* v2b  = (u16*)(ws + 33 * MB);
  u16* ctxb = (u16*)(ws + 34 * MB);   // [308][768] bf16 cast of ctx
  float* x2 = (float*)(ws + 32 * MB); // fp32 over k2b/v2b/ctxb -> 48 MB
  u16* gg   = (u16*)(ws + 48 * MB);   // [4096][4096] bf16 over ao+x1 -> 80 MB

  u16* WT0 = W;                        // 2 MB slots within W
  u16* WT1 = (u16*)(ws + 2 * MB);
  u16* WT2 = (u16*)(ws + 4 * MB);
  u16* WT3 = (u16*)(ws + 6 * MB);

  dim3 T256(256);
  // ================= attn1 (self) =================
  transpose_k<<<dim3(32, 32), T256, 0, stream>>>(a1wq, WT0, 1024, 1024);
  transpose_k<<<dim3(32, 32), T256, 0, stream>>>(a1wk, WT1, 1024, 1024);
  transpose_k<<<dim3(32, 32), T256, 0, stream>>>(a1wv, WT2, 1024, 1024);
  transpose_k<<<dim3(32, 32), T256, 0, stream>>>(a1wo, WT3, 1024, 1024);
  ln_k<<<4096, T256, 0, stream>>>(x, n1w, n1b, lnb);
  gemm_bt<0><<<dim3(32, 8), T256, 0, stream>>>(lnb, 1024, WT0, 1024, qb, 1024,
                                               nullptr, nullptr, 0, d1q, 4096,
                                               1024, 1024);
  gemm_bt<0><<<dim3(32, 8), T256, 0, stream>>>(lnb, 1024, WT1, 1024, kb, 1024,
                                               nullptr, nullptr, 0, d1k, 4096,
                                               1024, 1024);
  gemm_bt<0><<<dim3(32, 8), T256, 0, stream>>>(lnb, 1024, WT2, 1024, vb, 1024,
                                               nullptr, nullptr, 0, d1v, 4096,
                                               1024, 1024);
  attn_k<<<dim3(16, 16, 4), T256, 0, stream>>>(qb, kb, vb, ao, d1q, d1k, d1v,
                                               d1w, 1024);
  gemm_bt<1><<<dim3(32, 8), T256, 0, stream>>>(ao, 1024, WT3, 1024, x1, 1024,
                                               a1bo, x, 1024, nullptr, 4096,
                                               1024, 1024);
  // ================= attn2 (cross, CTX_N=77) =================
  transpose_k<<<dim3(32, 32), T256, 0, stream>>>(a2wq, WT0, 1024, 1024);
  transpose_k<<<dim3(32, 32), T256, 0, stream>>>(a2wo, WT1, 1024, 1024);
  transpose_k<<<dim3(32, 24), T256, 0, stream>>>(a2wk, WT2, 768, 1024);
  transpose_k<<<dim3(32, 24), T256, 0, stream>>>(a2wv, WT3, 768, 1024);
  ln_k<<<4096, T256, 0, stream>>>(x1, n2w, n2b, lnb);
  cast_k<<<231, T256, 0, stream>>>(ctx, ctxb);  // 308*768 = 231*1024 elements
  gemm_bt<0><<<dim3(32, 8), T256, 0, stream>>>(lnb, 1024, WT0, 1024, qb, 1024,
                                               nullptr, nullptr, 0, d2q, 4096,
                                               1024, 1024);
  gemm_bt<0><<<dim3(3, 8), T256, 0, stream>>>(ctxb, 768, WT2, 768, k2b, 1024,
                                              nullptr, nullptr, 0, d2k, 308,
                                              1024, 768);
  gemm_bt<0><<<dim3(3, 8), T256, 0, stream>>>(ctxb, 768, WT3, 768, v2b, 1024,
                                              nullptr, nullptr, 0, d2v, 308,
                                              1024, 768);
  attn_k<<<dim3(16, 16, 4), T256, 0, stream>>>(qb, k2b, v2b, ao, d2q, d2k, d2v,
                                               d2w, 77);
  gemm_bt<1><<<dim3(32, 8), T256, 0, stream>>>(ao, 1024, WT1, 1024, x2, 1024,
                                               a2bo, x1, 1024, nullptr, 4096,
                                               1024, 1024);
  // ================= GEGLU FF =================
  transpose_k<<<dim3(256, 32), T256, 0, stream>>>(ffw1, W, 1024, 8192);
  ln_k<<<4096, T256, 0, stream>>>(x2, n3w, n3b, lnb);
  ff1_geglu_k<<<dim3(32, 64), T256, 0, stream>>>(lnb, W, ffb1, gg, 4096);
  transpose_k<<<dim3(32, 128), T256, 0, stream>>>(ffw2, W, 4096, 1024);
  gemm_bt<1><<<dim3(32, 8), T256, 0, stream>>>(gg, 4096, W, 4096, d_out, 1024,
                                               ffb2, x2, 1024, nullptr, 4096,
                                               1024, 4096);
}